// Round 6
// baseline (296.062 us; speedup 1.0000x reference)
//
#include <hip/hip_runtime.h>
#include <hip/hip_bf16.h>

using bf16x8 = __attribute__((ext_vector_type(8))) short;
using f32x4  = __attribute__((ext_vector_type(4))) float;

#define DEVI __device__ __forceinline__

DEVI unsigned short bf16r(float f)
{
    return __builtin_bit_cast(unsigned short, __float2bfloat16(f));
}

DEVI bf16x8 cvt8(const f32x4 a, const f32x4 b)
{
    bf16x8 r;
#pragma unroll
    for (int j = 0; j < 4; ++j) {
        r[j]     = (short)bf16r(a[j]);
        r[4 + j] = (short)bf16r(b[j]);
    }
    return r;
}

// ---------------- gather: x[b][:] = bf16(E[inp[b]][:]) ----------------
__global__ __launch_bounds__(256) void k_gather(const float* __restrict__ E,
                                                const int* __restrict__ inp,
                                                unsigned short* __restrict__ x)
{
    const int b = blockIdx.x;
    const long r = inp[b];
    const f32x4 v = ((const f32x4*)(E + r * 1024L))[threadIdx.x];
    ushort4 o;
    o.x = bf16r(v[0]); o.y = bf16r(v[1]); o.z = bf16r(v[2]); o.w = bf16r(v[3]);
    ((ushort4*)(x + (long)b * 1024L))[threadIdx.x] = o;
}

// ---------------- fp32 -> bf16 bulk convert ----------------
__global__ __launch_bounds__(256) void k_cvt(const float* __restrict__ in,
                                             unsigned short* __restrict__ out)
{
    const long i = (blockIdx.x * 256L + threadIdx.x) * 8;
    const f32x4 a = *(const f32x4*)(in + i);
    const f32x4 b = *(const f32x4*)(in + i + 4);
    *(bf16x8*)(out + i) = cvt8(a, b);
}

// =====================================================================
// GEMM core: 128x128 tile, BK=64, 4 waves (2x2), both operands bf16 in LDS.
//   A: bf16 [M,K] -> global_load_lds (16B granules, swizzle pre-applied to
//      the GLOBAL source, linear LDS dest — rule #21).
//   B: fp32 [N,K] -> reg-staged (8 x f32x4 per thread, issued during prior
//      MFMA phase), cvt8 -> swizzled ds_write_b128 (swizzle on LDS write +
//      read side, same XOR involution).
// LDS row = 64 bf16 = 128B = 8 granules; slot = j ^ (row & 7).
// =====================================================================

DEVI bf16x8 lds_frag(const char* lds, int row, int j)
{
    return *(const bf16x8*)(lds + row * 128 + ((j ^ (row & 7)) << 4));
}

DEVI void mfma_tile(const char* sA, const char* sB, int l, int wr, int wc,
                    f32x4 (&acc)[4][4])
{
#pragma unroll
    for (int ks = 0; ks < 2; ++ks) {
        bf16x8 af[4], bq[4];
#pragma unroll
        for (int m = 0; m < 4; ++m)
            af[m] = lds_frag(sA, wr * 64 + m * 16 + (l & 15), ks * 4 + (l >> 4));
#pragma unroll
        for (int n = 0; n < 4; ++n)
            bq[n] = lds_frag(sB, wc * 64 + n * 16 + (l & 15), ks * 4 + (l >> 4));
#pragma unroll
        for (int m = 0; m < 4; ++m)
#pragma unroll
            for (int n = 0; n < 4; ++n)
                acc[m][n] = __builtin_amdgcn_mfma_f32_16x16x32_bf16(
                    af[m], bq[n], acc[m][n], 0, 0, 0);
    }
}

template <bool CLAMP>
DEVI void gemm_core(const unsigned short* __restrict__ A, long lda, long arow0,
                    const float* __restrict__ B, long ldb, long brow0, long bmax,
                    int ntiles, long kbase, int t, char* sA, char* sB,
                    f32x4 (&acc)[4][4])
{
    const int l = t & 63;
    const int wr = (t >> 7) & 1, wc = (t >> 6) & 1;

    // A: 4 DMA source pointers, global pre-swizzled; linear LDS dest.
    const unsigned short* ap[4];
#pragma unroll
    for (int i = 0; i < 4; ++i) {
        const int g = i * 256 + t, row = g >> 3, js = g & 7;
        ap[i] = A + (arow0 + row) * lda + kbase + (long)((js ^ (row & 7)) * 8);
    }
    // B: 4 reg-load pointers (NO global swizzle; swizzle applied at ds_write).
    const float* bp[4];
#pragma unroll
    for (int i = 0; i < 4; ++i) {
        const int g = i * 256 + t, row = g >> 3, j = g & 7;
        long br = brow0 + row;
        if (CLAMP) br = (br < bmax) ? br : (bmax - 1);
        bp[i] = B + br * ldb + kbase + (long)(j * 8);
    }

    f32x4 br0[4], br1[4];
#pragma unroll
    for (int i = 0; i < 4; ++i) {           // preload tile 0's B into regs
        br0[i] = *(const f32x4*)bp[i];
        br1[i] = *(const f32x4*)(bp[i] + 4);
        bp[i] += 64;
    }

    for (int ti = 0; ti < ntiles; ++ti) {
        __syncthreads();                    // all waves done reading prev tile
#pragma unroll
        for (int i = 0; i < 4; ++i)
            __builtin_amdgcn_global_load_lds(
                (const __attribute__((address_space(1))) void*)(ap[i]),
                (__attribute__((address_space(3))) void*)(sA + (i * 256 + t) * 16),
                16, 0, 0);
#pragma unroll
        for (int i = 0; i < 4; ++i) {       // cvt + swizzled LDS write (waits B regs)
            const int g = i * 256 + t, row = g >> 3, j = g & 7;
            *(bf16x8*)(sB + row * 128 + ((j ^ (row & 7)) << 4)) = cvt8(br0[i], br1[i]);
        }
        __syncthreads();                    // A DMA drained + B writes visible
#pragma unroll
        for (int i = 0; i < 4; ++i) ap[i] += 64;
        if (ti + 1 < ntiles) {
#pragma unroll
            for (int i = 0; i < 4; ++i) {   // next tile's B flies during MFMA
                br0[i] = *(const f32x4*)bp[i];
                br1[i] = *(const f32x4*)(bp[i] + 4);
                bp[i] += 64;
            }
        }
        mfma_tile(sA, sB, l, wr, wc, acc);
    }
}

// ---------------- gates GEMM: chunk z of (x@Wx^T | h0@Wh^T) ----------------
// 768 blocks: XCD-chunked swizzle (q=96,r=0); 4 consecutive L = 4 row-tiles
// of one weight strip on the SAME XCD.
__global__ __launch_bounds__(256, 3) void k_gates(
    const unsigned short* __restrict__ xb, const float* __restrict__ Wx,
    const unsigned short* __restrict__ h0b, const float* __restrict__ Wh,
    float* __restrict__ g0, float* __restrict__ g1, float* __restrict__ g2)
{
    __shared__ __align__(16) char sA[128 * 128];
    __shared__ __align__(16) char sB[128 * 128];
    const int t = threadIdx.x;
    const int bid = blockIdx.x;
    const int xcd = bid & 7, slot = bid >> 3;
    const int L = xcd * 96 + slot;
    const int mtile = L & 3;
    const int rest = L >> 2;
    const int ntile = rest & 63;
    const int z = rest >> 6;

    const unsigned short* A; const float* B; long lda, ldb, kbase; float* C;
    if (z == 0)      { A = xb;  lda = 1024; B = Wx; ldb = 1024; kbase = 0;    C = g0; }
    else if (z == 1) { A = h0b; lda = 2048; B = Wh; ldb = 2048; kbase = 0;    C = g1; }
    else             { A = h0b; lda = 2048; B = Wh; ldb = 2048; kbase = 1024; C = g2; }

    f32x4 acc[4][4] = {};
    gemm_core<false>(A, lda, (long)mtile * 128, B, ldb, (long)ntile * 128,
                     1L << 40, 16, kbase, t, sA, sB, acc);

    const int l = t & 63;
    const int wr = (t >> 7) & 1, wc = (t >> 6) & 1;
    const int lc = l & 15, r4 = (l >> 4) * 4;
#pragma unroll
    for (int n = 0; n < 4; ++n) {
        const long col = (long)ntile * 128 + wc * 64 + n * 16 + lc;
#pragma unroll
        for (int m = 0; m < 4; ++m) {
            const long row = (long)mtile * 128 + wr * 64 + m * 16 + r4;
#pragma unroll
            for (int r = 0; r < 4; ++r)
                C[(row + r) * 8192 + col] = acc[m][n][r];
        }
    }
}

// ---------------- decoder GEMM: out = hx @ Wd^T + bd ----------------
// 1572 blocks: bijective XCD-chunk swizzle (q=196, r=4, m204 formula).
__global__ __launch_bounds__(256, 3) void k_dec(
    const unsigned short* __restrict__ hxb, const float* __restrict__ Wd,
    const float* __restrict__ bd, float* __restrict__ out)
{
    __shared__ __align__(16) char sA[128 * 128];
    __shared__ __align__(16) char sB[128 * 128];
    const int t = threadIdx.x;
    const int bid = blockIdx.x;
    const int xcd = bid & 7, slot = bid >> 3;
    const int L = xcd * 196 + (xcd < 4 ? xcd : 4) + slot;
    const int mtile = L & 3;
    const int ntile = L >> 2;                  // 0..392
    const long N = 50257;

    f32x4 acc[4][4] = {};
    gemm_core<true>(hxb, 2048, (long)mtile * 128, Wd, 2048, (long)ntile * 128,
                    N, 32, 0, t, sA, sB, acc);

    const int l = t & 63;
    const int wr = (t >> 7) & 1, wc = (t >> 6) & 1;
    const int lc = l & 15, r4 = (l >> 4) * 4;
#pragma unroll
    for (int n = 0; n < 4; ++n) {
        const long col = (long)ntile * 128 + wc * 64 + n * 16 + lc;
        if (col >= N) continue;
        const float bias = bd[col];
#pragma unroll
        for (int m = 0; m < 4; ++m) {
            const long row = (long)mtile * 128 + wr * 64 + m * 16 + r4;
#pragma unroll
            for (int r = 0; r < 4; ++r)
                out[(row + r) * N + col] = acc[m][n][r] + bias;
        }
    }
}

// ---------------- elementwise LSTM cell: combine 3 partials + biases ----------------
__global__ __launch_bounds__(256) void k_lstm(
    const float* __restrict__ g0, const float* __restrict__ g1,
    const float* __restrict__ g2, const float* __restrict__ bx,
    const float* __restrict__ bh, const float* __restrict__ c0,
    float* __restrict__ hx, float* __restrict__ cx,
    unsigned short* __restrict__ hxb)
{
    const int i = blockIdx.x * 256 + threadIdx.x;
    const int b = i >> 9;
    const int hc = (i & 511) << 2;
    const long base = (long)b * 8192;

    f32x4 g[4];
#pragma unroll
    for (int gi = 0; gi < 4; ++gi) {
        const long off = base + gi * 2048 + hc;
        const int boff = gi * 2048 + hc;
        g[gi] = *(const f32x4*)(g0 + off);
        g[gi] += *(const f32x4*)(g1 + off);
        g[gi] += *(const f32x4*)(g2 + off);
        g[gi] += *(const f32x4*)(bx + boff);
        g[gi] += *(const f32x4*)(bh + boff);
    }
    const f32x4 c0v = *(const f32x4*)(c0 + (long)b * 2048 + hc);

    f32x4 cv, hv;
    ushort4 hb;
#pragma unroll
    for (int j = 0; j < 4; ++j) {
        const float fg = 1.f / (1.f + __expf(-g[0][j]));
        const float ig = 1.f / (1.f + __expf(-g[1][j]));
        const float og = 1.f / (1.f + __expf(-g[2][j]));
        const float e2 = __expf(2.f * g[3][j]);
        const float ct = 1.f - 2.f / (e2 + 1.f);
        const float c  = fg * c0v[j] + ig * ct;
        const float e2c = __expf(2.f * c);
        const float th  = 1.f - 2.f / (e2c + 1.f);
        cv[j] = c;
        hv[j] = og * th;
    }
    hb.x = bf16r(hv[0]); hb.y = bf16r(hv[1]); hb.z = bf16r(hv[2]); hb.w = bf16r(hv[3]);

    const long o = (long)b * 2048 + hc;
    *(f32x4*)(cx + o) = cv;
    *(f32x4*)(hx + o) = hv;
    *(ushort4*)(hxb + o) = hb;
}

// ---------------- launch ----------------
extern "C" void kernel_launch(void* const* d_in, const int* in_sizes, int n_in,
                              void* d_out, int out_size, void* d_ws, size_t ws_size,
                              hipStream_t stream)
{
    const int*   inp = (const int*)d_in[0];
    const float* h0  = (const float*)d_in[1];
    const float* c0  = (const float*)d_in[2];
    const float* E   = (const float*)d_in[3];
    const float* Wx  = (const float*)d_in[4];   // (8192,1024)
    const float* bx  = (const float*)d_in[5];
    const float* Wh  = (const float*)d_in[6];   // (8192,2048)
    const float* bh  = (const float*)d_in[7];
    const float* Wd  = (const float*)d_in[8];   // (50257,2048)
    const float* bd  = (const float*)d_in[9];

    float* out = (float*)d_out;                 // [512][50257]
    float* hx  = out + 512L * 50257L;           // [512][2048]
    float* cx  = hx + 512L * 2048L;

    // Scratch in the out region — all consumed before k_dec overwrites out:
    //   xb @ 0 (0.5MB), g0 @ 1M floats, g1 @ 5M, g2 @ 9M, h0b @ 13M floats.
    unsigned short* xb  = (unsigned short*)out;
    float* g0 = out + (1L << 20);
    float* g1 = out + (5L << 20);
    float* g2 = out + (9L << 20);
    unsigned short* h0b = (unsigned short*)(out + (13L << 20));
    // hxb read during k_dec (which writes out) -> lives in d_ws.
    unsigned short* hxb = (unsigned short*)d_ws;

    k_gather<<<512, 256, 0, stream>>>(E, inp, xb);
    k_cvt<<<512, 256, 0, stream>>>(h0, h0b);

    k_gates<<<768, 256, 0, stream>>>(xb, Wx, h0b, Wh, g0, g1, g2);

    k_lstm<<<1024, 256, 0, stream>>>(g0, g1, g2, bx, bh, c0, hx, cx, hxb);

    k_dec<<<1572, 256, 0, stream>>>(hxb, Wd, bd, out);
}

// Round 7
// 285.590 us; speedup vs baseline: 1.0367x; 1.0367x over previous
//
#include <hip/hip_runtime.h>
#include <hip/hip_bf16.h>

using bf16x8 = __attribute__((ext_vector_type(8))) short;
using f32x4  = __attribute__((ext_vector_type(4))) float;

#define DEVI __device__ __forceinline__

DEVI unsigned short bf16r(float f)
{
    return __builtin_bit_cast(unsigned short, __float2bfloat16(f));
}

DEVI bf16x8 cvt8(const f32x4 a, const f32x4 b)
{
    bf16x8 r;
#pragma unroll
    for (int j = 0; j < 4; ++j) {
        r[j]     = (short)bf16r(a[j]);
        r[4 + j] = (short)bf16r(b[j]);
    }
    return r;
}

// ---------------- gather: x[b][:] = bf16(E[inp[b]][:]) ----------------
__global__ __launch_bounds__(256) void k_gather(const float* __restrict__ E,
                                                const int* __restrict__ inp,
                                                unsigned short* __restrict__ x)
{
    const int b = blockIdx.x;
    const long r = inp[b];
    const f32x4 v = ((const f32x4*)(E + r * 1024L))[threadIdx.x];
    ushort4 o;
    o.x = bf16r(v[0]); o.y = bf16r(v[1]); o.z = bf16r(v[2]); o.w = bf16r(v[3]);
    ((ushort4*)(x + (long)b * 1024L))[threadIdx.x] = o;
}

// ---------------- fp32 -> bf16 bulk convert ----------------
__global__ __launch_bounds__(256) void k_cvt(const float* __restrict__ in,
                                             unsigned short* __restrict__ out)
{
    const long i = (blockIdx.x * 256L + threadIdx.x) * 8;
    const f32x4 a = *(const f32x4*)(in + i);
    const f32x4 b = *(const f32x4*)(in + i + 4);
    *(bf16x8*)(out + i) = cvt8(a, b);
}

// =====================================================================
// GEMM core: 128x128 tile, BK=64, 4 waves (2x2), 2-phase DOUBLE-BUFFERED.
//   Per tile: STAGE(next buffer) issued FIRST, then MFMA(current buffer),
//   then ONE __syncthreads (its implicit vmcnt(0)/lgkmcnt(0) is the drain).
//   A: bf16 via global_load_lds, global source pre-swizzled, linear LDS
//      dest (rule #21).  B: fp32 global -> regs (issued one phase ahead)
//      -> cvt8 -> swizzled ds_write_b128.
// LDS row = 64 bf16 = 128B = 8 granules; slot = j ^ (row & 7).
// 4 buffers x 16KB = 64KB -> 2 blocks/CU.
// =====================================================================

DEVI bf16x8 lds_frag(const char* lds, int row, int j)
{
    return *(const bf16x8*)(lds + row * 128 + ((j ^ (row & 7)) << 4));
}

DEVI void mfma_tile(const char* sA, const char* sB, int l, int wr, int wc,
                    f32x4 (&acc)[4][4])
{
#pragma unroll
    for (int ks = 0; ks < 2; ++ks) {
        bf16x8 af[4], bq[4];
#pragma unroll
        for (int m = 0; m < 4; ++m)
            af[m] = lds_frag(sA, wr * 64 + m * 16 + (l & 15), ks * 4 + (l >> 4));
#pragma unroll
        for (int n = 0; n < 4; ++n)
            bq[n] = lds_frag(sB, wc * 64 + n * 16 + (l & 15), ks * 4 + (l >> 4));
#pragma unroll
        for (int m = 0; m < 4; ++m)
#pragma unroll
            for (int n = 0; n < 4; ++n)
                acc[m][n] = __builtin_amdgcn_mfma_f32_16x16x32_bf16(
                    af[m], bq[n], acc[m][n], 0, 0, 0);
    }
}

template <bool CLAMP>
DEVI void gemm_core(const unsigned short* __restrict__ A, long lda, long arow0,
                    const float* __restrict__ B, long ldb, long brow0, long bmax,
                    int ntiles, long kbase, int t,
                    char* sA0, char* sB0, char* sA1, char* sB1,
                    f32x4 (&acc)[4][4])
{
    const int l = t & 63;
    const int wr = (t >> 7) & 1, wc = (t >> 6) & 1;

    // A: 4 DMA source pointers (global pre-swizzled), linear LDS dest.
    const unsigned short* ap[4];
#pragma unroll
    for (int i = 0; i < 4; ++i) {
        const int g = i * 256 + t, row = g >> 3, js = g & 7;
        ap[i] = A + (arow0 + row) * lda + kbase + (long)((js ^ (row & 7)) * 8);
    }
    // B: 4 linear global pointers + precomputed swizzled ds_write offsets.
    const float* bp[4];
    int swz[4];
#pragma unroll
    for (int i = 0; i < 4; ++i) {
        const int g = i * 256 + t, row = g >> 3, j = g & 7;
        long br = brow0 + row;
        if (CLAMP) br = (br < bmax) ? br : (bmax - 1);
        bp[i] = B + br * ldb + kbase + (long)(j * 8);
        swz[i] = row * 128 + ((j ^ (row & 7)) << 4);
    }

    f32x4 b0lo[4], b0hi[4], b1lo[4], b1hi[4];

#define LOADB(lo, hi)                                                          \
    do {                                                                       \
        _Pragma("unroll") for (int i = 0; i < 4; ++i) {                        \
            lo[i] = *(const f32x4*)bp[i];                                      \
            hi[i] = *(const f32x4*)(bp[i] + 4);                                \
            bp[i] += 64;                                                       \
        }                                                                      \
    } while (0)
#define DMA_A(buf)                                                             \
    do {                                                                       \
        _Pragma("unroll") for (int i = 0; i < 4; ++i) {                        \
            __builtin_amdgcn_global_load_lds(                                  \
                (const __attribute__((address_space(1))) void*)(ap[i]),        \
                (__attribute__((address_space(3))) void*)((buf) +              \
                                                          (i * 256 + t) * 16), \
                16, 0, 0);                                                     \
            ap[i] += 64;                                                       \
        }                                                                      \
    } while (0)
#define WRITEB(buf, lo, hi)                                                    \
    do {                                                                       \
        _Pragma("unroll") for (int i = 0; i < 4; ++i)                          \
            *(bf16x8*)((buf) + swz[i]) = cvt8(lo[i], hi[i]);                   \
    } while (0)

    // Prologue: tile0 -> buf0; issue B(1).
    LOADB(b0lo, b0hi);              // B(0)
    DMA_A(sA0);                     // A(0)
    WRITEB(sB0, b0lo, b0hi);        // waits B(0) regs
    LOADB(b1lo, b1hi);              // B(1) in flight
    __syncthreads();                // buf0 visible (vmcnt+lgkm drained)

    for (int ti = 0; ti < ntiles; ti += 2) {
        // EVEN: stage tile ti+1 -> buf1, compute tile ti (buf0).
        DMA_A(sA1);
        if (ti + 2 < ntiles) LOADB(b0lo, b0hi);      // B(ti+2) in flight
        WRITEB(sB1, b1lo, b1hi);                     // tile ti+1 (regs ready)
        mfma_tile(sA0, sB0, l, wr, wc, acc);
        __syncthreads();
        // ODD: stage tile ti+2 -> buf0, compute tile ti+1 (buf1).
        if (ti + 2 < ntiles) {
            DMA_A(sA0);
            if (ti + 3 < ntiles) LOADB(b1lo, b1hi);  // B(ti+3) in flight
            WRITEB(sB0, b0lo, b0hi);                 // tile ti+2
        }
        mfma_tile(sA1, sB1, l, wr, wc, acc);
        __syncthreads();
    }
#undef LOADB
#undef DMA_A
#undef WRITEB
}

// ---------------- gates GEMM: chunk z of (x@Wx^T | h0@Wh^T) ----------------
// 768 blocks: XCD-chunked swizzle (q=96,r=0); 4 consecutive L = 4 row-tiles
// of one weight strip on the SAME XCD.
__global__ __launch_bounds__(256, 2) void k_gates(
    const unsigned short* __restrict__ xb, const float* __restrict__ Wx,
    const unsigned short* __restrict__ h0b, const float* __restrict__ Wh,
    float* __restrict__ g0, float* __restrict__ g1, float* __restrict__ g2)
{
    __shared__ __align__(16) char sA0[128 * 128], sB0[128 * 128];
    __shared__ __align__(16) char sA1[128 * 128], sB1[128 * 128];
    const int t = threadIdx.x;
    const int bid = blockIdx.x;
    const int xcd = bid & 7, slot = bid >> 3;
    const int L = xcd * 96 + slot;
    const int mtile = L & 3;
    const int rest = L >> 2;
    const int ntile = rest & 63;
    const int z = rest >> 6;

    const unsigned short* A; const float* B; long lda, ldb, kbase; float* C;
    if (z == 0)      { A = xb;  lda = 1024; B = Wx; ldb = 1024; kbase = 0;    C = g0; }
    else if (z == 1) { A = h0b; lda = 2048; B = Wh; ldb = 2048; kbase = 0;    C = g1; }
    else             { A = h0b; lda = 2048; B = Wh; ldb = 2048; kbase = 1024; C = g2; }

    f32x4 acc[4][4] = {};
    gemm_core<false>(A, lda, (long)mtile * 128, B, ldb, (long)ntile * 128,
                     1L << 40, 16, kbase, t, sA0, sB0, sA1, sB1, acc);

    const int l = t & 63;
    const int wr = (t >> 7) & 1, wc = (t >> 6) & 1;
    const int lc = l & 15, r4 = (l >> 4) * 4;
#pragma unroll
    for (int n = 0; n < 4; ++n) {
        const long col = (long)ntile * 128 + wc * 64 + n * 16 + lc;
#pragma unroll
        for (int m = 0; m < 4; ++m) {
            const long row = (long)mtile * 128 + wr * 64 + m * 16 + r4;
#pragma unroll
            for (int r = 0; r < 4; ++r)
                C[(row + r) * 8192 + col] = acc[m][n][r];
        }
    }
}

// ---------------- decoder GEMM: out = hx @ Wd^T + bd ----------------
// 1572 blocks: bijective XCD-chunk swizzle (q=196, r=4, m204 formula).
__global__ __launch_bounds__(256, 2) void k_dec(
    const unsigned short* __restrict__ hxb, const float* __restrict__ Wd,
    const float* __restrict__ bd, float* __restrict__ out)
{
    __shared__ __align__(16) char sA0[128 * 128], sB0[128 * 128];
    __shared__ __align__(16) char sA1[128 * 128], sB1[128 * 128];
    const int t = threadIdx.x;
    const int bid = blockIdx.x;
    const int xcd = bid & 7, slot = bid >> 3;
    const int L = xcd * 196 + (xcd < 4 ? xcd : 4) + slot;
    const int mtile = L & 3;
    const int ntile = L >> 2;                  // 0..392
    const long N = 50257;

    f32x4 acc[4][4] = {};
    gemm_core<true>(hxb, 2048, (long)mtile * 128, Wd, 2048, (long)ntile * 128,
                    N, 32, 0, t, sA0, sB0, sA1, sB1, acc);

    const int l = t & 63;
    const int wr = (t >> 7) & 1, wc = (t >> 6) & 1;
    const int lc = l & 15, r4 = (l >> 4) * 4;
#pragma unroll
    for (int n = 0; n < 4; ++n) {
        const long col = (long)ntile * 128 + wc * 64 + n * 16 + lc;
        if (col >= N) continue;
        const float bias = bd[col];
#pragma unroll
        for (int m = 0; m < 4; ++m) {
            const long row = (long)mtile * 128 + wr * 64 + m * 16 + r4;
#pragma unroll
            for (int r = 0; r < 4; ++r)
                out[(row + r) * N + col] = acc[m][n][r] + bias;
        }
    }
}

// ---------------- elementwise LSTM cell: combine 3 partials + biases ----------------
__global__ __launch_bounds__(256) void k_lstm(
    const float* __restrict__ g0, const float* __restrict__ g1,
    const float* __restrict__ g2, const float* __restrict__ bx,
    const float* __restrict__ bh, const float* __restrict__ c0,
    float* __restrict__ hx, float* __restrict__ cx,
    unsigned short* __restrict__ hxb)
{
    const int i = blockIdx.x * 256 + threadIdx.x;
    const int b = i >> 9;
    const int hc = (i & 511) << 2;
    const long base = (long)b * 8192;

    f32x4 g[4];
#pragma unroll
    for (int gi = 0; gi < 4; ++gi) {
        const long off = base + gi * 2048 + hc;
        const int boff = gi * 2048 + hc;
        g[gi] = *(const f32x4*)(g0 + off);
        g[gi] += *(const f32x4*)(g1 + off);
        g[gi] += *(const f32x4*)(g2 + off);
        g[gi] += *(const f32x4*)(bx + boff);
        g[gi] += *(const f32x4*)(bh + boff);
    }
    const f32x4 c0v = *(const f32x4*)(c0 + (long)b * 2048 + hc);

    f32x4 cv, hv;
    ushort4 hb;
#pragma unroll
    for (int j = 0; j < 4; ++j) {
        const float fg = 1.f / (1.f + __expf(-g[0][j]));
        const float ig = 1.f / (1.f + __expf(-g[1][j]));
        const float og = 1.f / (1.f + __expf(-g[2][j]));
        const float e2 = __expf(2.f * g[3][j]);
        const float ct = 1.f - 2.f / (e2 + 1.f);
        const float c  = fg * c0v[j] + ig * ct;
        const float e2c = __expf(2.f * c);
        const float th  = 1.f - 2.f / (e2c + 1.f);
        cv[j] = c;
        hv[j] = og * th;
    }
    hb.x = bf16r(hv[0]); hb.y = bf16r(hv[1]); hb.z = bf16r(hv[2]); hb.w = bf16r(hv[3]);

    const long o = (long)b * 2048 + hc;
    *(f32x4*)(cx + o) = cv;
    *(f32x4*)(hx + o) = hv;
    *(ushort4*)(hxb + o) = hb;
}

// ---------------- launch ----------------
extern "C" void kernel_launch(void* const* d_in, const int* in_sizes, int n_in,
                              void* d_out, int out_size, void* d_ws, size_t ws_size,
                              hipStream_t stream)
{
    const int*   inp = (const int*)d_in[0];
    const float* h0  = (const float*)d_in[1];
    const float* c0  = (const float*)d_in[2];
    const float* E   = (const float*)d_in[3];
    const float* Wx  = (const float*)d_in[4];   // (8192,1024)
    const float* bx  = (const float*)d_in[5];
    const float* Wh  = (const float*)d_in[6];   // (8192,2048)
    const float* bh  = (const float*)d_in[7];
    const float* Wd  = (const float*)d_in[8];   // (50257,2048)
    const float* bd  = (const float*)d_in[9];

    float* out = (float*)d_out;                 // [512][50257]
    float* hx  = out + 512L * 50257L;           // [512][2048]
    float* cx  = hx + 512L * 2048L;

    // Scratch in the out region — all consumed before k_dec overwrites out:
    //   xb @ 0 (0.5MB), g0 @ 1M floats, g1 @ 5M, g2 @ 9M, h0b @ 13M floats.
    unsigned short* xb  = (unsigned short*)out;
    float* g0 = out + (1L << 20);
    float* g1 = out + (5L << 20);
    float* g2 = out + (9L << 20);
    unsigned short* h0b = (unsigned short*)(out + (13L << 20));
    // hxb read during k_dec (which writes out) -> lives in d_ws.
    unsigned short* hxb = (unsigned short*)d_ws;

    k_gather<<<512, 256, 0, stream>>>(E, inp, xb);
    k_cvt<<<512, 256, 0, stream>>>(h0, h0b);

    k_gates<<<768, 256, 0, stream>>>(xb, Wx, h0b, Wh, g0, g1, g2);

    k_lstm<<<1024, 256, 0, stream>>>(g0, g1, g2, bx, bh, c0, hx, cx, hxb);

    k_dec<<<1572, 256, 0, stream>>>(hxb, Wd, bd, out);
}